// Round 2
// baseline (1519.126 us; speedup 1.0000x reference)
//
#include <hip/hip_runtime.h>
#include <hip/hip_bf16.h>

#define NUM_AA    20
#define NUM_PAIRS 400   // 20*20
#define DD        64    // embedding dim
#define NT        1024  // threads per block
#define NW        16    // waves per block
#define UNROLL    8

// One block per batch row b. Histogram [400][64] fp32 (100 KiB) in LDS,
// reused across the k+1 gap values. lane = d (64 lanes == D), waves take
// contiguous position chunks. Each position is loaded ONCE per t-pass and
// scatter-added to its left-pair and right-pair buckets (edge weights
// predicated to zero; seq staged with 4-element zero pads on both ends).
__global__ __launch_bounds__(NT, 4)
void cksaap_kernel(const int* __restrict__ seq,
                   const float* __restrict__ emb,
                   float* __restrict__ out,
                   int B, int L, int k)
{
    __shared__ float hist[NUM_PAIRS * DD];   // 102400 B
    __shared__ int   s_seq[2048 + 8];        // [4 pad][L][4 pad]

    const int b    = blockIdx.x;
    const int tid  = threadIdx.x;
    const int lane = tid & 63;
    const int wave = tid >> 6;               // 0..15
    const int T    = k + 1;

    // stage sequence once, zero-pad both ends
    for (int i = tid; i < L; i += NT) s_seq[4 + i] = seq[(size_t)b * L + i];
    if (tid < 4) { s_seq[tid] = 0; s_seq[4 + L + tid] = 0; }
    for (int i = tid; i < NUM_PAIRS * DD; i += NT) hist[i] = 0.0f;
    __syncthreads();

    const float* embb = emb + (size_t)b * L * DD;

    const int chunk = (L + NW - 1) / NW;     // 128 for L=2048
    const int start = wave * chunk;
    const int end   = min(start + chunk, L);

    for (int t = 0; t < T; ++t) {
        const int n = L - t - 1;

        for (int i0 = start; i0 < end; i0 += UNROLL) {
            float v[UNROLL];
            #pragma unroll
            for (int u = 0; u < UNROLL; ++u) {
                const int j = i0 + u;
                v[u] = (j < end) ? embb[(size_t)j * DD + lane] : 0.0f;
            }
            #pragma unroll
            for (int u = 0; u < UNROLL; ++u) {
                const int j = i0 + u;
                if (j < end) {
                    const int sj = s_seq[4 + j];             // this residue
                    const int sr = s_seq[4 + j + t + 1];     // right partner
                    const int sl = s_seq[4 + j - t - 1];     // left partner
                    // j is left member of pair (j, j+t+1) when j < n
                    const float vl = (j < n)     ? v[u] : 0.0f;
                    // j is right member of pair (j-t-1, j) when j >= t+1
                    const float vr = (j >= t + 1) ? v[u] : 0.0f;
                    atomicAdd(&hist[(sj * NUM_AA + sr) * DD + lane], vl);
                    atomicAdd(&hist[(sl * NUM_AA + sj) * DD + lane], vr);
                }
            }
        }
        __syncthreads();

        // store (0.5 folded into scale) + re-zero for next t
        const float scale = 0.5f / (float)n;
        float* outp = out + ((size_t)b * T + t) * NUM_PAIRS * DD;
        for (int i = tid; i < NUM_PAIRS * DD; i += NT) {
            outp[i] = hist[i] * scale;
            hist[i] = 0.0f;
        }
        __syncthreads();
    }
}

extern "C" void kernel_launch(void* const* d_in, const int* in_sizes, int n_in,
                              void* d_out, int out_size, void* d_ws, size_t ws_size,
                              hipStream_t stream)
{
    const int*   seq = (const int*)d_in[0];
    const float* emb = (const float*)d_in[1];
    float*       out = (float*)d_out;

    const int B = 256;
    const int L = in_sizes[0] / B;                        // 2048
    const int k = out_size / (B * NUM_PAIRS * DD) - 1;    // 3

    cksaap_kernel<<<B, NT, 0, stream>>>(seq, emb, out, B, L, k);
}

// Round 3
// 300.412 us; speedup vs baseline: 5.0568x; 5.0568x over previous
//
#include <hip/hip_runtime.h>
#include <hip/hip_bf16.h>

#define NUM_AA    20
#define NUM_PAIRS 400
#define DD        64
#define NT        512   // threads per block
#define NW        8     // waves per block
#define LMAX      2048

// One block per (b, t). Counting-sort positions by pair-bucket, then each
// wave gather-accumulates its buckets in registers (lane = d). No float
// atomics, 23 KB LDS -> 4 blocks/CU, full occupancy.
__global__ __launch_bounds__(NT, 8)
void cksaap_kernel(const int* __restrict__ seq,
                   const float* __restrict__ emb,
                   float* __restrict__ out,
                   int B, int L, int k)
{
    __shared__ int            s_seq[LMAX];       // 8 KB
    __shared__ unsigned short s_idx[LMAX];       // 4 KB  bucket of position j
    __shared__ unsigned short s_ord[LMAX];       // 4 KB  positions sorted by bucket
    __shared__ int            s_cnt[NUM_PAIRS];  // 1.6 KB
    __shared__ int            s_off[NUM_PAIRS];  // 1.6 KB exclusive offsets
    __shared__ int            s_cur[NUM_PAIRS];  // 1.6 KB scatter cursors
    __shared__ int            s_scan[NT];        // 2 KB

    const int T   = k + 1;
    const int nwg = gridDim.x;
    const int i   = blockIdx.x;
    int b, t;
    if (nwg == 1024 && T == 4) {
        // XCD-aware: put the 4 t-blocks of one b on the same XCD (i%8 mapping)
        const int x = i & 7;
        const int s = i >> 3;     // 0..127
        t = s >> 5;               // 0..3
        b = x * 32 + (s & 31);    // 0..255
    } else {
        b = i / T; t = i % T;
    }

    const int tid  = threadIdx.x;
    const int lane = tid & 63;
    const int wave = tid >> 6;
    const int n    = L - t - 1;

    // phase 1: stage seq row, zero counts
    for (int j = tid; j < L; j += NT) s_seq[j] = seq[(size_t)b * L + j];
    if (tid < NUM_PAIRS) s_cnt[tid] = 0;
    __syncthreads();

    // phase 2: bucket index per position + histogram counts (int atomics)
    for (int j = tid; j < n; j += NT) {
        const int idx = s_seq[j] * NUM_AA + s_seq[j + t + 1];
        s_idx[j] = (unsigned short)idx;
        atomicAdd(&s_cnt[idx], 1);
    }
    __syncthreads();

    // phase 3: exclusive prefix scan of counts (Hillis-Steele over 512)
    const int c0 = (tid < NUM_PAIRS) ? s_cnt[tid] : 0;
    s_scan[tid] = c0;
    __syncthreads();
    for (int off = 1; off < NT; off <<= 1) {
        int v = s_scan[tid];
        if (tid >= off) v += s_scan[tid - off];
        __syncthreads();
        s_scan[tid] = v;
        __syncthreads();
    }
    if (tid < NUM_PAIRS) {
        const int excl = s_scan[tid] - c0;
        s_off[tid] = excl;
        s_cur[tid] = excl;
    }
    __syncthreads();

    // phase 4: scatter position ids into bucket-sorted order
    for (int j = tid; j < n; j += NT) {
        const int idx = s_idx[j];
        const int r   = atomicAdd(&s_cur[idx], 1);
        s_ord[r] = (unsigned short)j;
    }
    __syncthreads();

    // phase 5: per-bucket register gather-accumulate + coalesced store
    const float  scale = 0.5f / (float)n;
    const float* embb  = emb + (size_t)b * L * DD;
    float*       outp  = out + ((size_t)b * T + t) * (size_t)(NUM_PAIRS * DD);

    for (int p = wave; p < NUM_PAIRS; p += NW) {
        const int base = s_off[p];
        const int cnt  = s_cnt[p];
        float acc = 0.0f;
        int m = 0;
        for (; m + 4 <= cnt; m += 4) {
            const int j0 = s_ord[base + m + 0];
            const int j1 = s_ord[base + m + 1];
            const int j2 = s_ord[base + m + 2];
            const int j3 = s_ord[base + m + 3];
            const float a0 = embb[(size_t)j0 * DD + lane];
            const float b0 = embb[(size_t)(j0 + t + 1) * DD + lane];
            const float a1 = embb[(size_t)j1 * DD + lane];
            const float b1 = embb[(size_t)(j1 + t + 1) * DD + lane];
            const float a2 = embb[(size_t)j2 * DD + lane];
            const float b2 = embb[(size_t)(j2 + t + 1) * DD + lane];
            const float a3 = embb[(size_t)j3 * DD + lane];
            const float b3 = embb[(size_t)(j3 + t + 1) * DD + lane];
            acc += (a0 + b0) + (a1 + b1) + ((a2 + b2) + (a3 + b3));
        }
        for (; m < cnt; ++m) {
            const int j = s_ord[base + m];
            acc += embb[(size_t)j * DD + lane] +
                   embb[(size_t)(j + t + 1) * DD + lane];
        }
        outp[(size_t)p * DD + lane] = acc * scale;
    }
}

extern "C" void kernel_launch(void* const* d_in, const int* in_sizes, int n_in,
                              void* d_out, int out_size, void* d_ws, size_t ws_size,
                              hipStream_t stream)
{
    const int*   seq = (const int*)d_in[0];
    const float* emb = (const float*)d_in[1];
    float*       out = (float*)d_out;

    const int B = 256;
    const int L = in_sizes[0] / B;                        // 2048
    const int k = out_size / (B * NUM_PAIRS * DD) - 1;    // 3

    cksaap_kernel<<<B * (k + 1), NT, 0, stream>>>(seq, emb, out, B, L, k);
}